// Round 9
// baseline (180.988 us; speedup 1.0000x reference)
//
#include <hip/hip_runtime.h>
#include <hip/hip_bf16.h>
#include <stdint.h>

typedef int i32x4 __attribute__((ext_vector_type(4)));

// ---------------------------------------------------------------------------
// Pass 1: binarize f32 -> i8 sign (+1 / -1 / 0), both tensors in ONE dispatch
// (HBM-bound; fused to save a launch gap)
// ---------------------------------------------------------------------------
__device__ __forceinline__ signed char sign_i8(float x) {
  return x > 0.0f ? (signed char)1 : (x < 0.0f ? (signed char)-1 : (signed char)0);
}

__global__ void binarize_i8_all(const float* __restrict__ x,
                                const float* __restrict__ w,
                                signed char* __restrict__ xb,
                                signed char* __restrict__ wb,
                                int n8x, int n8t) {
  int idx = blockIdx.x * blockDim.x + threadIdx.x;
  int stride = gridDim.x * blockDim.x;
  for (int i = idx; i < n8t; i += stride) {
    const float4* in4;
    uint2* out2;
    int j;
    if (i < n8x) { in4 = (const float4*)x; out2 = (uint2*)xb; j = i; }
    else         { in4 = (const float4*)w; out2 = (uint2*)wb; j = i - n8x; }
    float4 a = in4[2 * j];
    float4 b = in4[2 * j + 1];
    union { signed char c[8]; uint2 u; } p;
    p.c[0] = sign_i8(a.x); p.c[1] = sign_i8(a.y);
    p.c[2] = sign_i8(a.z); p.c[3] = sign_i8(a.w);
    p.c[4] = sign_i8(b.x); p.c[5] = sign_i8(b.y);
    p.c[6] = sign_i8(b.z); p.c[7] = sign_i8(b.w);
    out2[j] = p.u;
  }
}

// ---------------------------------------------------------------------------
// Pass 2: C = A * B^T, i8 +-1 inputs, i32 acc, f32 out (exact).
// 256x256 tile, BK=64 (i8), 8 waves (2Mx4N), 4-buffer LDS rotation (128 KiB),
// counted vmcnt, XOR-swizzled LDS, ONE barrier per K-tile.
// Round 9: cross-tile FRAGMENT pipeline. B-fragments (bf, 16 VGPR) are kept
// one tile ahead in registers; per iteration the af reads of tile tt and the
// bf prefetch of tile tt+1 drain on the LDS pipe UNDER the 32-MFMA cluster
// (bf_cur already in regs, so MFMA m starts after af[m] alone -> compiler's
// fine lgkmcnt waits interleave reads with MFMAs instead of serializing a
// CU-wide read phase (1130 cyc) before the MFMA phase (1306 cyc)).
// Buffer safety: reads of buf (tt-1)&3 are lgkm-complete before the MFMAs
// that consume them (iter tt-1), which precede bar(tt); stage(tt+3) into
// that buffer is issued after bar(tt). Staging visibility: each wave
// vmcnt-waits its own tile-(tt+1) loads before bar, so after bar the whole
// tile is in LDS for everyone.
// __launch_bounds__(512,2): 256-reg/wave budget. acc(128 AGPR) + af(32) +
// bf_cur/bf_nxt(32) + addressing ~= 244 unified. Do NOT request more
// waves/EU: (512,4) forced a 128-reg cap -> acc spill -> 3.3 GB scratch
// (round 7). Do NOT prefetch af too: +32 regs > 256 -> occupancy halves.
// ---------------------------------------------------------------------------
__device__ __forceinline__ void load_lds16(const void* g, void* l) {
  __builtin_amdgcn_global_load_lds(
      (const __attribute__((address_space(1))) void*)g,
      (__attribute__((address_space(3))) void*)l,
      16, 0, 0);
}

__device__ __forceinline__ void bar() {
  asm volatile("s_barrier" ::: "memory");
}
template <int N>
__device__ __forceinline__ void waitvm() {
  asm volatile("s_waitcnt vmcnt(%0)" ::"i"(N) : "memory");
}

__global__ __launch_bounds__(512, 2)
void gemm_bt_i8(const signed char* __restrict__ A,
                const signed char* __restrict__ B,
                float* __restrict__ C,
                int M, int N, int K, int nbn) {
  constexpr int BM = 256, BN = 256, BK = 64;
  __shared__ __attribute__((aligned(16))) char lds[4 * 32768];

  // XCD-aware bijective swizzle (grid = 32*16 = 512, multiple of 8)
  int nwg = gridDim.x;
  int bid = blockIdx.x;
  int cpx = nwg >> 3;
  int swz = (bid & 7) * cpx + (bid >> 3);
  int tm = swz / nbn;
  int tn = swz % nbn;

  const int t = threadIdx.x;
  const int lane = t & 63;
  const int wid = t >> 6;       // 0..7
  const int wm = wid >> 2;      // 0..1  (wave row: 128 rows)
  const int wn = wid & 3;       // 0..3  (wave col: 64 cols)
  const int lrow = lane & 15;
  const int kg = lane >> 4;     // 0..3 (16 contiguous k-bytes each)

  const size_t rowA0 = (size_t)tm * BM;
  const size_t rowB0 = (size_t)tn * BN;

  i32x4 acc[8][4] = {};

  const int nt = K / BK;  // 64

  // --- staging lane constants (inverse-swizzled global source) ---
  const int soff0 = wid * 1024 + lane * 16;
  const int srow0 = soff0 >> 6;
  const int scb0 = ((soff0 >> 4) & 3) ^ ((srow0 >> 1) & 3);
  const int soff1 = 8192 + wid * 1024 + lane * 16;
  const int srow1 = soff1 >> 6;
  const int scb1 = ((soff1 >> 4) & 3) ^ ((srow1 >> 1) & 3);

  auto stage = [&](int tt) {
    const int b = tt & 3;
    const int k0 = tt * BK;
    load_lds16(A + (rowA0 + srow0) * K + k0 + scb0 * 16,
               lds + b * 32768 + wid * 1024);
    load_lds16(A + (rowA0 + srow1) * K + k0 + scb1 * 16,
               lds + b * 32768 + 8192 + wid * 1024);
    load_lds16(B + (rowB0 + srow0) * K + k0 + scb0 * 16,
               lds + b * 32768 + 16384 + wid * 1024);
    load_lds16(B + (rowB0 + srow1) * K + k0 + scb1 * 16,
               lds + b * 32768 + 16384 + 8192 + wid * 1024);
  };

  // --- swizzled read column (byte) within a 64B LDS row ---
  const int rcol = ((kg ^ ((lrow >> 1) & 3)) << 4);
  const int aoff = (wm * 128 + lrow) * 64 + rcol;
  const int boff = 16384 + (wn * 64 + lrow) * 64 + rcol;

  // prologue: stage tiles 0,1; sync tile 0; prefetch its B frags; stage 2
  stage(0); stage(1);
  waitvm<4>();
  bar();
  i32x4 bf_cur[4];
  {
    const char* Bb = lds + boff;  // buffer 0
    #pragma unroll
    for (int n = 0; n < 4; ++n)
      bf_cur[n] = *(const i32x4*)(Bb + n * 1024);
  }
  stage(2);

  for (int tt = 0; tt < nt; ++tt) {
    const int b = tt & 3;
    const int b1 = (tt + 1) & 3;

    // issue af reads for tile tt (readiness ensured at iter tt-1's bar)
    const char* Ab = lds + b * 32768 + aoff;
    i32x4 af[8];
    #pragma unroll
    for (int m = 0; m < 8; ++m)
      af[m] = *(const i32x4*)(Ab + m * 1024);

    i32x4 bf_nxt[4];
    if (tt + 1 < nt) {
      // tile tt+1 staged: own loads vmcnt-waited, then barrier
      if (tt + 2 < nt) waitvm<4>(); else waitvm<0>();
      bar();
      if (tt + 3 < nt) stage(tt + 3);
      const char* Bb = lds + b1 * 32768 + boff;
      #pragma unroll
      for (int n = 0; n < 4; ++n)
        bf_nxt[n] = *(const i32x4*)(Bb + n * 1024);
    }

    // MFMA cluster: m-outer so MFMA m waits only on af[m] (bf_cur in regs);
    // LDS pipe drains af + bf_nxt under this cluster.
    #pragma unroll
    for (int m = 0; m < 8; ++m)
      #pragma unroll
      for (int n = 0; n < 4; ++n)
        acc[m][n] = __builtin_amdgcn_mfma_i32_16x16x64_i8(af[m], bf_cur[n], acc[m][n], 0, 0, 0);

    #pragma unroll
    for (int n = 0; n < 4; ++n)
      bf_cur[n] = bf_nxt[n];
  }

  // --- epilogue: C/D layout col = lane&15, row = (lane>>4)*4 + r ---
  // i32 -> f32 conversion is exact (|sum| <= 4096)
  const size_t cRow0 = rowA0 + (size_t)wm * 128;
  const size_t cCol0 = rowB0 + (size_t)wn * 64;
  const int orow = kg * 4;
  #pragma unroll
  for (int m = 0; m < 8; ++m)
    #pragma unroll
    for (int n = 0; n < 4; ++n)
      #pragma unroll
      for (int r = 0; r < 4; ++r)
        C[(cRow0 + m * 16 + orow + r) * N + cCol0 + n * 16 + lrow] =
            (float)acc[m][n][r];
}

// ---------------------------------------------------------------------------
extern "C" void kernel_launch(void* const* d_in, const int* in_sizes, int n_in,
                              void* d_out, int out_size, void* d_ws, size_t ws_size,
                              hipStream_t stream) {
  const float* x = (const float*)d_in[0];
  const float* w = (const float*)d_in[1];
  float* out = (float*)d_out;

  const int K = 4096;
  const int M = in_sizes[0] / K;   // 8192
  const int N = in_sizes[1] / K;   // 4096

  signed char* xb = (signed char*)d_ws;
  signed char* wb = xb + (size_t)M * K;

  int n8x = (M * K) / 8;
  int n8t = n8x + (N * K) / 8;
  binarize_i8_all<<<dim3(2048), dim3(256), 0, stream>>>(x, w, xb, wb, n8x, n8t);

  int nbm = M / 256;
  int nbn = N / 256;
  gemm_bt_i8<<<dim3(nbm * nbn), dim3(512), 0, stream>>>(
      xb, wb, out, M, N, K, nbn);
}